// Round 8
// baseline (30.347 us; speedup 1.0000x reference)
//
#include <hip/hip_runtime.h>
#include <stdint.h>

#define WW 19
#define NP 361
#define M19 0x7FFFFu
#define BPW 3                  // boards per wave in row phase (3*19 = 57 lanes)
#define NWAVES 4
#define BPB 12                 // boards per block (4 waves * 3)
#define TPB 256
#define CHF (BPB * 722)        // 8664 floats per full stone chunk
#define CH4 (CHF / 4)          // 2166 float4s
#define BMW 272                // bitmap dwords (8664 bits = 270.75 -> 271, +1 pad)
#define PLSTR 97               // u32 stride for row-planes in LDS

typedef float f32x4 __attribute__((ext_vector_type(4)));

__device__ __forceinline__ uint32_t rev19(uint32_t x) { return __brev(x) >> 13; }

// Fill every horizontal run of m containing a seed of g (g subset of m).
__device__ __forceinline__ uint32_t runfill(uint32_t g, uint32_t m) {
  const uint32_t up = g | (m & ((m + g) ^ m ^ g));
  const uint32_t rm = rev19(m);
  const uint32_t rg = rev19(g);
  const uint32_t dn = rg | (rm & ((rm + rg) ^ rm ^ rg));
  return up | rev19(dn);
}

__global__ __launch_bounds__(TPB, 4) void go_fused(
    const float* __restrict__ stones, const int* __restrict__ cur,
    const int* __restrict__ ko, const int* __restrict__ zob,
    const int* __restrict__ zturn, const int* __restrict__ phash,
    float* __restrict__ out, int B) {
  __shared__ uint32_t bmp[BMW];          // linear stone bitmap: cell i = bit i
  __shared__ uint32_t pl[BPB * PLSTR];   // row planes: L0,L1,L2,legal,groups

  const int wid = threadIdx.x >> 6;
  const int lane = threadIdx.x & 63;
  const int b0 = blockIdx.x * BPB;
  const int nb = min(BPB, B - b0);
  const size_t NB = (size_t)B * NP;

  // Zobrist tables preloaded into registers (uniform across blocks, cached).
  int zb[6], zw[6];
#pragma unroll
  for (int i = 0; i < 6; ++i) {
    const int p = i * 64 + lane;
    zb[i] = (p < NP) ? zob[p] : 0;
    zw[i] = (p < NP) ? zob[NP + p] : 0;
  }
  const int zt = zturn[0] ^ zturn[1];

  // ---------------- phase 1: float4 loads -> bit nibbles -> LDS bitmap ------
  // No zero-init needed: writer lanes cover all bitmap dwords 0..270 (beyond-
  // range lanes contribute m=0); dword 271 is alignment padding, never used.
  {
    const f32x4* src = (const f32x4*)(stones + (size_t)b0 * 722);
    const int nf4 = nb * 722 / 4;  // nb is always even
    for (int j = 0; j < (CH4 + TPB - 1) / TPB; ++j) {
      const int q = threadIdx.x + TPB * j;
      uint32_t m = 0;
      if (q < nf4) {
        const f32x4 v = src[q];
        m = (uint32_t)(v.x > 0.5f) | ((uint32_t)(v.y > 0.5f) << 1) |
            ((uint32_t)(v.z > 0.5f) << 2) | ((uint32_t)(v.w > 0.5f) << 3);
      }
      // Butterfly combine 8 consecutive threads' nibbles into one dword.
      uint32_t x = m | ((uint32_t)__shfl_xor((int)m, 1, 64) << 4);
      x = x | ((uint32_t)__shfl_xor((int)x, 2, 64) << 8);
      x = x | ((uint32_t)__shfl_xor((int)x, 4, 64) << 16);
      if ((lane & 7) == 0 && q < CH4) bmp[q >> 3] = x;
    }
  }
  __syncthreads();

  // ---------------- phase 1.5: zobrist hash from bitmap (wave per 3 boards) -
  {
    int hv[BPW];
#pragma unroll
    for (int k = 0; k < BPW; ++k) {
      const int lb = wid * BPW + k;
      const uint32_t base = lb * 722;
      int h = 0;
#pragma unroll
      for (int i = 0; i < 6; ++i) {
        const int cc = i * 64 + lane;
        if (cc < NP) {
          uint32_t pos = base + cc;
          uint32_t s = (bmp[pos >> 5] >> (pos & 31)) & 1u;
          h ^= zb[i] & -(int)s;
          pos = base + 361 + cc;
          s = (bmp[pos >> 5] >> (pos & 31)) & 1u;
          h ^= zw[i] & -(int)s;
        }
      }
      hv[k] = h;
    }
#pragma unroll
    for (int off = 32; off > 0; off >>= 1) {
#pragma unroll
      for (int k = 0; k < BPW; ++k) hv[k] ^= __shfl_xor(hv[k], off, 64);
    }
    if (lane == 0) {
#pragma unroll
      for (int k = 0; k < BPW; ++k) {
        const int b = b0 + wid * BPW + k;
        if (b < B) out[3 * NB + b] = (float)(phash[b] ^ hv[k] ^ zt);
      }
    }
  }

  // ---------------- phase 2: row-per-lane bitboard algebra + flood ----------
  {
    const int k = (lane * 27) >> 9;  // lane / 19
    const int r = lane - k * WW;
    const int lb = wid * BPW + k;
    const int b = b0 + lb;
    const bool vl = (lane < 57) && (lb < nb);
    const int lbs = vl ? lb : 0;

    // Extract this lane's black/white rows from the bitmap (funnel shift).
    uint32_t brow, wrow;
    {
      const uint32_t base = (uint32_t)lbs * 722 + (uint32_t)r * WW;
      const uint32_t d = base >> 5, sh = base & 31;
      const uint64_t w = ((uint64_t)bmp[d + 1] << 32) | bmp[d];
      brow = (uint32_t)(w >> sh) & M19;
      const uint32_t base2 = base + 361;
      const uint32_t d2 = base2 >> 5, sh2 = base2 & 31;
      const uint64_t w2 = ((uint64_t)bmp[d2 + 1] << 32) | bmp[d2];
      wrow = (uint32_t)(w2 >> sh2) & M19;
    }
    const int cp = vl ? cur[b] : 0;
    int2 kk = {-1, -1};
    if (vl) kk = ((const int2*)ko)[b];
    uint32_t mrow = (cp == 0) ? wrow : brow;
    uint32_t erow = ~(brow | wrow) & M19;
    if (!vl) { mrow = 0; erow = 0; }

    // Liberties / legal / vulnerable (vertical neighbors via shfl).
    uint32_t t;
    t = __shfl(erow, lane - 1, 64);
    const uint32_t eu = (r > 0) ? t : 0u;
    t = __shfl(erow, lane + 1, 64);
    const uint32_t ed = (r < 18) ? t : 0u;
    const uint32_t el = (erow << 1) & M19;
    const uint32_t er_ = erow >> 1;
    const uint32_t s1 = eu ^ ed, c1 = eu & ed;
    const uint32_t s2 = el ^ er_, c2 = el & er_;
    const uint32_t cc = s1 & s2;
    const uint32_t L0 = s1 ^ s2;
    const uint32_t L1 = c1 ^ c2 ^ cc;
    const uint32_t L2 = (c1 & c2) | (cc & (c1 | c2));
    uint32_t leg = erow & (eu | ed | el | er_);
    const uint32_t vul = mrow & L0 & ~L1;  // liberty count == 1
    t = __shfl(vul, lane - 1, 64);
    const uint32_t vu = (r > 0) ? t : 0u;
    t = __shfl(vul, lane + 1, 64);
    const uint32_t vd = (r < 18) ? t : 0u;
    leg |= erow & (vu | vd | ((vul << 1) & M19) | (vul >> 1));
    if (kk.x == r) leg &= ~(1u << kk.y);

    // Flood fill: horizontal runfill + vertical shfl step, early exit.
    uint32_t g = runfill(vul, mrow);
    for (int it = 0; it < 90; ++it) {
      t = __shfl(g, lane - 1, 64);
      const uint32_t gu = (r > 0) ? t : 0u;
      t = __shfl(g, lane + 1, 64);
      const uint32_t gd = (r < 18) ? t : 0u;
      const uint32_t gn = runfill(g | ((gu | gd) & mrow), mrow);
      if (!__any(gn != g)) break;
      g = gn;
    }

    if (vl) {
      uint32_t* pb = &pl[lb * PLSTR];
      pb[r] = L0;
      pb[19 + r] = L1;
      pb[38 + r] = L2;
      pb[57 + r] = leg;
      pb[76 + r] = g;
    }
  }
  __syncthreads();

  // ---------------- phase 3: expand LDS row-planes -> float4 nt stores ------
  {
    const int nq = nb * NP / 4;  // exact when nb % 4 == 0 (12 and 4 tails)
    f32x4* s0 = (f32x4*)(out + (size_t)b0 * NP);
    f32x4* s1 = (f32x4*)(out + NB + (size_t)b0 * NP);
    f32x4* s2 = (f32x4*)(out + 2 * NB + (size_t)b0 * NP);
    for (int q = threadIdx.x; q < nq; q += TPB) {
      f32x4 t0, t1, t2;
#pragma unroll
      for (int j = 0; j < 4; ++j) {
        const int id = q * 4 + j;
        const int lb = (int)(((uint64_t)id * 5948986ull) >> 31);  // id/361
        const int p = id - lb * NP;
        const int r = (p * 27) >> 9;  // p/19 for p<512
        const int c = p - r * WW;
        const uint32_t* pb = &pl[lb * PLSTR];
        const uint32_t l0 = (pb[r] >> c) & 1u;
        const uint32_t l1 = (pb[19 + r] >> c) & 1u;
        const uint32_t l2 = (pb[38 + r] >> c) & 1u;
        t0[j] = (float)(l0 + 2u * l1 + 4u * l2);
        t1[j] = (float)((pb[57 + r] >> c) & 1u);
        t2[j] = (float)((pb[76 + r] >> c) & 1u);
      }
      __builtin_nontemporal_store(t0, &s0[q]);
      __builtin_nontemporal_store(t1, &s1[q]);
      __builtin_nontemporal_store(t2, &s2[q]);
    }
    // Generic remainder guard (unused for B=16384, kept for safety).
    const int rem0 = nq * 4;
    for (int id = rem0 + threadIdx.x; id < nb * NP; id += TPB) {
      const int lb = (int)(((uint64_t)id * 5948986ull) >> 31);
      const int p = id - lb * NP;
      const int r = (p * 27) >> 9;
      const int c = p - r * WW;
      const uint32_t* pb = &pl[lb * PLSTR];
      const uint32_t l0 = (pb[r] >> c) & 1u;
      const uint32_t l1 = (pb[19 + r] >> c) & 1u;
      const uint32_t l2 = (pb[38 + r] >> c) & 1u;
      out[(size_t)b0 * NP + id] = (float)(l0 + 2u * l1 + 4u * l2);
      out[NB + (size_t)b0 * NP + id] = (float)((pb[57 + r] >> c) & 1u);
      out[2 * NB + (size_t)b0 * NP + id] = (float)((pb[76 + r] >> c) & 1u);
    }
  }
}

extern "C" void kernel_launch(void* const* d_in, const int* in_sizes, int n_in,
                              void* d_out, int out_size, void* d_ws,
                              size_t ws_size, hipStream_t stream) {
  const float* stones = (const float*)d_in[0];
  const int* cur = (const int*)d_in[1];
  const int* ko = (const int*)d_in[2];
  const int* zob = (const int*)d_in[3];
  const int* zturn = (const int*)d_in[4];
  const int* phash = (const int*)d_in[5];
  float* out = (float*)d_out;

  const int B = in_sizes[0] / (2 * NP);
  const int blocks = (B + BPB - 1) / BPB;
  go_fused<<<blocks, TPB, 0, stream>>>(stones, cur, ko, zob, zturn, phash, out,
                                       B);
}

// Round 9
// 29.373 us; speedup vs baseline: 1.0332x; 1.0332x over previous
//
#include <hip/hip_runtime.h>
#include <stdint.h>

#define WW 19
#define NP 361
#define M19 0x7FFFFu
#define BPB 3     // boards per block (one wave)
#define TPB 64
#define PLSTR 97  // u32 stride for row-planes in LDS
#define BMW 69    // bitmap dwords: 3*722 = 2166 bits -> 68 dwords + 1 pad

__device__ __forceinline__ uint32_t rev19(uint32_t x) { return __brev(x) >> 13; }

// Fill every horizontal run of m containing a seed of g (g subset of m).
__device__ __forceinline__ uint32_t runfill(uint32_t g, uint32_t m) {
  const uint32_t up = g | (m & ((m + g) ^ m ^ g));
  const uint32_t rm = rev19(m);
  const uint32_t rg = rev19(g);
  const uint32_t dn = rg | (rm & ((rm + rg) ^ rm ^ rg));
  return up | rev19(dn);
}

// One wave per 3 boards; zero __syncthreads (all LDS handoffs wave-synchronous).
__global__ __launch_bounds__(TPB, 4) void go_wave(
    const float* __restrict__ stones, const int* __restrict__ cur,
    const int* __restrict__ ko, const int* __restrict__ zob,
    const int* __restrict__ zturn, const int* __restrict__ phash,
    float* __restrict__ out, int B) {
  __shared__ uint32_t bmp[BMW];         // linear stone bitmap for 3 boards
  __shared__ uint32_t pl[BPB * PLSTR];  // row planes: L0,L1,L2,legal,groups

  const int lane = threadIdx.x;
  const int b0 = blockIdx.x * BPB;
  const int nb = min(BPB, B - b0);
  const size_t NB = (size_t)B * NP;

  // Zobrist tables preloaded (uniform across blocks; L1/L2-hot).
  int zb[6], zw[6];
#pragma unroll
  for (int i = 0; i < 6; ++i) {
    const int p = i * 64 + lane;
    zb[i] = (p < NP) ? zob[p] : 0;
    zw[i] = (p < NP) ? zob[NP + p] : 0;
  }
  const int zt = zturn[0] ^ zturn[1];

  // ---------------- phase 1: float2 loads -> 2-bit pairs -> LDS bitmap ------
  {
    const float2* src = (const float2*)(stones + (size_t)b0 * 722);
    const int nf2 = nb * 361;  // float2 count (2166 floats / 2 for nb=3)
#pragma unroll
    for (int j = 0; j < 17; ++j) {
      const int q = j * 64 + lane;
      uint32_t m = 0;
      if (q < nf2) {
        const float2 v = src[q];
        m = (uint32_t)(v.x > 0.5f) | ((uint32_t)(v.y > 0.5f) << 1);
      }
      // Combine 16 consecutive lanes' 2-bit pairs into one dword.
      uint32_t x = m | ((uint32_t)__shfl_xor((int)m, 1, 64) << 2);
      x |= (uint32_t)__shfl_xor((int)x, 2, 64) << 4;
      x |= (uint32_t)__shfl_xor((int)x, 4, 64) << 8;
      x |= (uint32_t)__shfl_xor((int)x, 8, 64) << 16;
      if ((lane & 15) == 0) bmp[j * 4 + (lane >> 4)] = x;
    }
  }

  // ---------------- phase 1.5: zobrist hash from bitmap ---------------------
  {
    int hv0 = 0, hv1 = 0, hv2 = 0;
#pragma unroll
    for (int i = 0; i < 6; ++i) {
      const int cc = i * 64 + lane;
      if (cc < NP) {
        uint32_t pos, s;
        pos = cc;        s = (bmp[pos >> 5] >> (pos & 31)) & 1u; hv0 ^= zb[i] & -(int)s;
        pos = cc + 361;  s = (bmp[pos >> 5] >> (pos & 31)) & 1u; hv0 ^= zw[i] & -(int)s;
        pos = cc + 722;  s = (bmp[pos >> 5] >> (pos & 31)) & 1u; hv1 ^= zb[i] & -(int)s;
        pos = cc + 1083; s = (bmp[pos >> 5] >> (pos & 31)) & 1u; hv1 ^= zw[i] & -(int)s;
        pos = cc + 1444; s = (bmp[pos >> 5] >> (pos & 31)) & 1u; hv2 ^= zb[i] & -(int)s;
        pos = cc + 1805; s = (bmp[pos >> 5] >> (pos & 31)) & 1u; hv2 ^= zw[i] & -(int)s;
      }
    }
#pragma unroll
    for (int off = 32; off > 0; off >>= 1) {
      hv0 ^= __shfl_xor(hv0, off, 64);
      hv1 ^= __shfl_xor(hv1, off, 64);
      hv2 ^= __shfl_xor(hv2, off, 64);
    }
    if (lane < nb) {
      const int h = (lane == 0) ? hv0 : (lane == 1) ? hv1 : hv2;
      out[3 * NB + b0 + lane] = (float)(phash[b0 + lane] ^ h ^ zt);
    }
  }

  // ---------------- phase 2: row-per-lane bitboard algebra + flood ----------
  {
    const int k = (lane * 27) >> 9;  // lane / 19
    const int r = lane - k * WW;
    const int b = b0 + k;
    const bool vl = (lane < 57) && (k < nb);
    const int ks = vl ? k : 0;

    // Extract this lane's black/white rows from the bitmap (funnel shift).
    uint32_t brow, wrow;
    {
      const uint32_t base = (uint32_t)ks * 722 + (uint32_t)r * WW;
      const uint32_t d = base >> 5, sh = base & 31;
      const uint64_t w = ((uint64_t)bmp[d + 1] << 32) | bmp[d];
      brow = (uint32_t)(w >> sh) & M19;
      const uint32_t base2 = base + 361;
      const uint32_t d2 = base2 >> 5, sh2 = base2 & 31;
      const uint64_t w2 = ((uint64_t)bmp[d2 + 1] << 32) | bmp[d2];
      wrow = (uint32_t)(w2 >> sh2) & M19;
    }
    const int cp = vl ? cur[b] : 0;
    int2 kk = {-1, -1};
    if (vl) kk = ((const int2*)ko)[b];
    uint32_t mrow = (cp == 0) ? wrow : brow;
    uint32_t erow = ~(brow | wrow) & M19;
    if (!vl) { mrow = 0; erow = 0; }

    // Liberties / legal / vulnerable (vertical neighbors via shfl).
    uint32_t t;
    t = __shfl(erow, lane - 1, 64);
    const uint32_t eu = (r > 0) ? t : 0u;
    t = __shfl(erow, lane + 1, 64);
    const uint32_t ed = (r < 18) ? t : 0u;
    const uint32_t el = (erow << 1) & M19;
    const uint32_t er_ = erow >> 1;
    const uint32_t s1 = eu ^ ed, c1 = eu & ed;
    const uint32_t s2 = el ^ er_, c2 = el & er_;
    const uint32_t cc = s1 & s2;
    const uint32_t L0 = s1 ^ s2;
    const uint32_t L1 = c1 ^ c2 ^ cc;
    const uint32_t L2 = (c1 & c2) | (cc & (c1 | c2));
    uint32_t leg = erow & (eu | ed | el | er_);
    const uint32_t vul = mrow & L0 & ~L1;  // liberty count == 1
    t = __shfl(vul, lane - 1, 64);
    const uint32_t vu = (r > 0) ? t : 0u;
    t = __shfl(vul, lane + 1, 64);
    const uint32_t vd = (r < 18) ? t : 0u;
    leg |= erow & (vu | vd | ((vul << 1) & M19) | (vul >> 1));
    if (kk.x == r) leg &= ~(1u << kk.y);

    // Flood fill: horizontal runfill + vertical shfl step, early exit.
    uint32_t g = runfill(vul, mrow);
    for (int it = 0; it < 90; ++it) {
      t = __shfl(g, lane - 1, 64);
      const uint32_t gu = (r > 0) ? t : 0u;
      t = __shfl(g, lane + 1, 64);
      const uint32_t gd = (r < 18) ? t : 0u;
      const uint32_t gn = runfill(g | ((gu | gd) & mrow), mrow);
      if (!__any(gn != g)) break;
      g = gn;
    }

    if (vl) {
      uint32_t* pb = &pl[k * PLSTR];
      pb[r] = L0;
      pb[19 + r] = L1;
      pb[38 + r] = L2;
      pb[57 + r] = leg;
      pb[76 + r] = g;
    }
  }

  // ---------------- phase 3: expand LDS row-planes -> coalesced stores ------
  {
#pragma unroll
    for (int j = 0; j < 6; ++j) {
      const int p = j * 64 + lane;
      const bool ok = p < NP;
      const int r = ok ? ((p * 27) >> 9) : 0;  // p/19
      const int c = p - r * WW;
#pragma unroll
      for (int k = 0; k < BPB; ++k) {
        if (ok && k < nb) {
          const uint32_t* pb = &pl[k * PLSTR];
          const uint32_t l0 = (pb[r] >> c) & 1u;
          const uint32_t l1 = (pb[19 + r] >> c) & 1u;
          const uint32_t l2 = (pb[38 + r] >> c) & 1u;
          const size_t o = (size_t)(b0 + k) * NP + p;
          out[o] = (float)(l0 + 2u * l1 + 4u * l2);
          out[NB + o] = (float)((pb[57 + r] >> c) & 1u);
          out[2 * NB + o] = (float)((pb[76 + r] >> c) & 1u);
        }
      }
    }
  }
}

extern "C" void kernel_launch(void* const* d_in, const int* in_sizes, int n_in,
                              void* d_out, int out_size, void* d_ws,
                              size_t ws_size, hipStream_t stream) {
  const float* stones = (const float*)d_in[0];
  const int* cur = (const int*)d_in[1];
  const int* ko = (const int*)d_in[2];
  const int* zob = (const int*)d_in[3];
  const int* zturn = (const int*)d_in[4];
  const int* phash = (const int*)d_in[5];
  float* out = (float*)d_out;

  const int B = in_sizes[0] / (2 * NP);
  const int blocks = (B + BPB - 1) / BPB;
  go_wave<<<blocks, TPB, 0, stream>>>(stones, cur, ko, zob, zturn, phash, out,
                                      B);
}

// Round 10
// 28.842 us; speedup vs baseline: 1.0522x; 1.0184x over previous
//
#include <hip/hip_runtime.h>
#include <stdint.h>

#define WW 19
#define NP 361
#define M19 0x7FFFFu
#define BPW 3                 // boards per wave in row phase (3*19 = 57 lanes)
#define NWAVES 4
#define BPB 12                // boards per block
#define TPB 256
#define STGF (BPB * 722)      // 8664 staged floats
#define PLSTR 97              // u32 stride for row-planes in LDS

typedef float f32x4 __attribute__((ext_vector_type(4)));

__device__ __forceinline__ uint32_t rev19(uint32_t x) { return __brev(x) >> 13; }

// Fill every horizontal run of m containing a seed of g (g subset of m).
__device__ __forceinline__ uint32_t runfill(uint32_t g, uint32_t m) {
  const uint32_t up = g | (m & ((m + g) ^ m ^ g));
  const uint32_t rm = rev19(m);
  const uint32_t rg = rev19(g);
  const uint32_t dn = rg | (rm & ((rm + rg) ^ rm ^ rg));
  return up | rev19(dn);
}

__global__ __launch_bounds__(TPB, 4) void go_fused(
    const float* __restrict__ stones, const int* __restrict__ cur,
    const int* __restrict__ ko, const int* __restrict__ zob,
    const int* __restrict__ zturn, const int* __restrict__ phash,
    float* __restrict__ out, int B) {
  __shared__ float stg[STGF];           // raw staged stone floats (12 boards)
  __shared__ uint32_t pl[BPB * PLSTR];  // row planes: L0,L1,L2,legal,groups

  const int wid = threadIdx.x >> 6;
  const int lane = threadIdx.x & 63;
  const int b0 = blockIdx.x * BPB;
  const int nb = min(BPB, B - b0);
  const size_t NB = (size_t)B * NP;

  // Zobrist tables preloaded into registers (uniform across blocks, cached).
  int zb[6], zw[6];
#pragma unroll
  for (int i = 0; i < 6; ++i) {
    const int p = i * 64 + lane;
    zb[i] = (p < NP) ? zob[p] : 0;
    zw[i] = (p < NP) ? zob[NP + p] : 0;
  }
  const int zt = zturn[0] ^ zturn[1];

  // ---------------- phase 1: async global->LDS staging (raw floats) ---------
  // Each round: one wave-uniform global_load_lds dwordx4 (64 lanes x 16 B).
  // Zero VGPR round-trip; ~34.7 KB in flight per block.
  {
    const uint32_t nfl = (uint32_t)nb * 722u;
    const float* gsrc = stones + (size_t)b0 * 722;
#pragma unroll
    for (int rnd = 0; rnd < 9; ++rnd) {
      const uint32_t fo = (uint32_t)rnd * 1024u + (uint32_t)wid * 256u +
                          (uint32_t)lane * 4u;
      if (fo < nfl) {
        __builtin_amdgcn_global_load_lds(
            (const __attribute__((address_space(1))) uint32_t*)(gsrc + fo),
            (__attribute__((address_space(3))) uint32_t*)(stg + rnd * 1024 +
                                                          wid * 256),
            16, 0, 0);
      }
    }
  }
  __syncthreads();  // drains vmcnt; staged floats visible block-wide

  // ---------------- phase 1.5: zobrist hash from staged floats --------------
  {
    int hv[BPW];
#pragma unroll
    for (int k = 0; k < BPW; ++k) {
      const int lb = wid * BPW + k;
      const int base = lb * 722;
      int h = 0;
#pragma unroll
      for (int i = 0; i < 6; ++i) {
        const int cc = i * 64 + lane;
        if (cc < NP) {
          const uint32_t sb = stg[base + cc] > 0.5f;
          const uint32_t sw = stg[base + 361 + cc] > 0.5f;
          h ^= zb[i] & -(int)sb;
          h ^= zw[i] & -(int)sw;
        }
      }
      hv[k] = h;
    }
#pragma unroll
    for (int off = 32; off > 0; off >>= 1) {
#pragma unroll
      for (int k = 0; k < BPW; ++k) hv[k] ^= __shfl_xor(hv[k], off, 64);
    }
    if (lane == 0) {
#pragma unroll
      for (int k = 0; k < BPW; ++k) {
        const int b = b0 + wid * BPW + k;
        if (b < B) out[3 * NB + b] = (float)(phash[b] ^ hv[k] ^ zt);
      }
    }
  }

  // ---------------- phase 2: row-per-lane bitboard algebra + flood ----------
  {
    const int k = (lane * 27) >> 9;  // lane / 19
    const int r = lane - k * WW;
    const int lb = wid * BPW + k;
    const int b = b0 + lb;
    const bool vl = (lane < 57) && (lb < nb);
    const int lbs = vl ? lb : 0;

    // Build this lane's black/white rows from staged floats.
    uint32_t brow = 0, wrow = 0;
    {
      const float* rb = &stg[lbs * 722 + r * WW];
#pragma unroll
      for (int c = 0; c < WW; ++c) {
        brow |= (uint32_t)(rb[c] > 0.5f) << c;
        wrow |= (uint32_t)(rb[361 + c] > 0.5f) << c;
      }
    }
    const int cp = vl ? cur[b] : 0;
    int2 kk = {-1, -1};
    if (vl) kk = ((const int2*)ko)[b];
    uint32_t mrow = (cp == 0) ? wrow : brow;
    uint32_t erow = ~(brow | wrow) & M19;
    if (!vl) { mrow = 0; erow = 0; }

    // Liberties / legal / vulnerable (vertical neighbors via shfl).
    uint32_t t;
    t = __shfl(erow, lane - 1, 64);
    const uint32_t eu = (r > 0) ? t : 0u;
    t = __shfl(erow, lane + 1, 64);
    const uint32_t ed = (r < 18) ? t : 0u;
    const uint32_t el = (erow << 1) & M19;
    const uint32_t er_ = erow >> 1;
    const uint32_t s1 = eu ^ ed, c1 = eu & ed;
    const uint32_t s2 = el ^ er_, c2 = el & er_;
    const uint32_t cc = s1 & s2;
    const uint32_t L0 = s1 ^ s2;
    const uint32_t L1 = c1 ^ c2 ^ cc;
    const uint32_t L2 = (c1 & c2) | (cc & (c1 | c2));
    uint32_t leg = erow & (eu | ed | el | er_);
    const uint32_t vul = mrow & L0 & ~L1;  // liberty count == 1
    t = __shfl(vul, lane - 1, 64);
    const uint32_t vu = (r > 0) ? t : 0u;
    t = __shfl(vul, lane + 1, 64);
    const uint32_t vd = (r < 18) ? t : 0u;
    leg |= erow & (vu | vd | ((vul << 1) & M19) | (vul >> 1));
    if (kk.x == r) leg &= ~(1u << kk.y);

    // Flood fill: horizontal runfill + vertical shfl step, early exit.
    uint32_t g = runfill(vul, mrow);
    for (int it = 0; it < 90; ++it) {
      t = __shfl(g, lane - 1, 64);
      const uint32_t gu = (r > 0) ? t : 0u;
      t = __shfl(g, lane + 1, 64);
      const uint32_t gd = (r < 18) ? t : 0u;
      const uint32_t gn = runfill(g | ((gu | gd) & mrow), mrow);
      if (!__any(gn != g)) break;
      g = gn;
    }

    if (vl) {
      uint32_t* pb = &pl[lb * PLSTR];
      pb[r] = L0;
      pb[19 + r] = L1;
      pb[38 + r] = L2;
      pb[57 + r] = leg;
      pb[76 + r] = g;
    }
  }
  __syncthreads();

  // ---------------- phase 3: expand LDS row-planes -> float4 nt stores ------
  {
    const int nq = nb * NP / 4;  // nb in {12,4} -> always divisible
    f32x4* s0 = (f32x4*)(out + (size_t)b0 * NP);
    f32x4* s1 = (f32x4*)(out + NB + (size_t)b0 * NP);
    f32x4* s2 = (f32x4*)(out + 2 * NB + (size_t)b0 * NP);
    for (int q = threadIdx.x; q < nq; q += TPB) {
      f32x4 t0, t1, t2;
#pragma unroll
      for (int j = 0; j < 4; ++j) {
        const int id = q * 4 + j;
        const int lb = (int)(((uint64_t)id * 5948986ull) >> 31);  // id/361
        const int p = id - lb * NP;
        const int r = (p * 27) >> 9;  // p/19 for p<512
        const int c = p - r * WW;
        const uint32_t* pb = &pl[lb * PLSTR];
        const uint32_t l0 = (pb[r] >> c) & 1u;
        const uint32_t l1 = (pb[19 + r] >> c) & 1u;
        const uint32_t l2 = (pb[38 + r] >> c) & 1u;
        t0[j] = (float)(l0 + 2u * l1 + 4u * l2);
        t1[j] = (float)((pb[57 + r] >> c) & 1u);
        t2[j] = (float)((pb[76 + r] >> c) & 1u);
      }
      __builtin_nontemporal_store(t0, &s0[q]);
      __builtin_nontemporal_store(t1, &s1[q]);
      __builtin_nontemporal_store(t2, &s2[q]);
    }
    // Generic remainder guard (never taken for nb in {12,4}; safety only).
    const int rem0 = nq * 4;
    for (int id = rem0 + threadIdx.x; id < nb * NP; id += TPB) {
      const int lb = (int)(((uint64_t)id * 5948986ull) >> 31);
      const int p = id - lb * NP;
      const int r = (p * 27) >> 9;
      const int c = p - r * WW;
      const uint32_t* pb = &pl[lb * PLSTR];
      const uint32_t l0 = (pb[r] >> c) & 1u;
      const uint32_t l1 = (pb[19 + r] >> c) & 1u;
      const uint32_t l2 = (pb[38 + r] >> c) & 1u;
      out[(size_t)b0 * NP + id] = (float)(l0 + 2u * l1 + 4u * l2);
      out[NB + (size_t)b0 * NP + id] = (float)((pb[57 + r] >> c) & 1u);
      out[2 * NB + (size_t)b0 * NP + id] = (float)((pb[76 + r] >> c) & 1u);
    }
  }
}

extern "C" void kernel_launch(void* const* d_in, const int* in_sizes, int n_in,
                              void* d_out, int out_size, void* d_ws,
                              size_t ws_size, hipStream_t stream) {
  const float* stones = (const float*)d_in[0];
  const int* cur = (const int*)d_in[1];
  const int* ko = (const int*)d_in[2];
  const int* zob = (const int*)d_in[3];
  const int* zturn = (const int*)d_in[4];
  const int* phash = (const int*)d_in[5];
  float* out = (float*)d_out;

  const int B = in_sizes[0] / (2 * NP);
  const int blocks = (B + BPB - 1) / BPB;
  go_fused<<<blocks, TPB, 0, stream>>>(stones, cur, ko, zob, zturn, phash, out,
                                       B);
}